// Round 2
// baseline (246.090 us; speedup 1.0000x reference)
//
#include <hip/hip_runtime.h>

typedef __bf16 bf16_t;
typedef __bf16 bf16x8 __attribute__((ext_vector_type(8)));
typedef __bf16 bf16x4 __attribute__((ext_vector_type(4)));
typedef float f32x4 __attribute__((ext_vector_type(4)));

#define GLB_AS(p) ((const __attribute__((address_space(1))) unsigned int*)(p))
#define LDS_AS(p) ((__attribute__((address_space(3))) unsigned int*)(p))

// ---------------- fp32 -> bf16 convert (vectorized), optional scale ----------------
__global__ void cvt_bf16_kernel(const float* __restrict__ in, bf16_t* __restrict__ out, int n, float scale)
{
    int i = (blockIdx.x * blockDim.x + threadIdx.x) * 4;
    if (i >= n) return;
    float4 v = *(const float4*)(in + i);
    bf16x4 o;
    o[0] = (bf16_t)(v.x * scale); o[1] = (bf16_t)(v.y * scale);
    o[2] = (bf16_t)(v.z * scale); o[3] = (bf16_t)(v.w * scale);
    *(bf16x4*)(out + i) = o;
}

// ---------------- weight transpose: in f32 [R][C] -> out bf16 [C][R] ----------------
__global__ void wtrans_kernel(const float* __restrict__ in, bf16_t* __restrict__ out, int R, int C)
{
    __shared__ float tile[32][33];
    const int tid = threadIdx.x;
    const int r0 = blockIdx.y * 32, c0 = blockIdx.x * 32;
#pragma unroll
    for (int j = 0; j < 4; j++) {
        int r = j * 8 + (tid >> 5), c = tid & 31;
        tile[r][c] = in[(size_t)(r0 + r) * C + c0 + c];
    }
    __syncthreads();
#pragma unroll
    for (int j = 0; j < 4; j++) {
        int c = j * 8 + (tid >> 5), r = tid & 31;
        out[(size_t)(c0 + c) * R + r0 + r] = (bf16_t)tile[r][c];
    }
}

// ---------------- V transpose: QKV cols 1024..1535 -> Vt[bh][64][2048] ----------------
__global__ void vtrans_kernel(const bf16_t* __restrict__ qkv, bf16_t* __restrict__ vt)
{
    __shared__ bf16_t t[64][68];
    const int tid = threadIdx.x;
    const int lk0 = blockIdx.x * 64;
    const int bh = blockIdx.y, b = bh >> 3, h = bh & 7;
#pragma unroll
    for (int j = 0; j < 16; j++) {
        int e = j * 256 + tid;
        int lk_i = e >> 6, d = e & 63;
        t[lk_i][d] = qkv[(size_t)(b * 2048 + lk0 + lk_i) * 1536 + 1024 + h * 64 + d];
    }
    __syncthreads();
#pragma unroll
    for (int j = 0; j < 16; j++) {
        int e = j * 256 + tid;
        int d_i = e >> 6, lk = e & 63;
        vt[((size_t)bh * 64 + d_i) * 2048 + lk0 + lk] = t[lk][d_i];
    }
}

// ---------------- GEMM: C[M][N] = A[M][K] @ Bt[N][K]^T  (m97 structure) ----------------
template<bool SPLITA, bool BIAS, bool RELU, bool OUTBF16>
__global__ __launch_bounds__(256)
void gemm_kernel(const bf16_t* __restrict__ A0, const bf16_t* __restrict__ A1, int nsplit,
                 const bf16_t* __restrict__ Bt, const float* __restrict__ bias,
                 void* __restrict__ Cout, int K, int ldC)
{
    __shared__ __align__(16) bf16_t As[128 * 32];
    __shared__ __align__(16) bf16_t Bs[128 * 32];
    const int bm = blockIdx.x, bn = blockIdx.y;
    const bf16_t* A = (!SPLITA || bn < nsplit) ? A0 : A1;
    const int tid = threadIdx.x;
    const int lane = tid & 63;
    const int wid = tid >> 6;
    const int wr = wid >> 1, wc = wid & 1;

    f32x4 acc[4][4] = {};

    const int c0 = wid * 2;
    const int lb0 = c0 * 1024 + lane * 16;
    const int row0 = lb0 >> 6, col0 = (lb0 & 63) >> 1;
    const int lb1 = lb0 + 1024;
    const int row1 = lb1 >> 6, col1 = (lb1 & 63) >> 1;

    const bf16_t* Abase = A + (size_t)(bm * 128) * K;
    const bf16_t* Bbase = Bt + (size_t)(bn * 128) * K;

    for (int k0 = 0; k0 < K; k0 += 32) {
        __builtin_amdgcn_global_load_lds(GLB_AS(Abase + (size_t)row0 * K + k0 + col0), LDS_AS(As + c0 * 512), 16, 0, 0);
        __builtin_amdgcn_global_load_lds(GLB_AS(Abase + (size_t)row1 * K + k0 + col1), LDS_AS(As + c0 * 512 + 512), 16, 0, 0);
        __builtin_amdgcn_global_load_lds(GLB_AS(Bbase + (size_t)row0 * K + k0 + col0), LDS_AS(Bs + c0 * 512), 16, 0, 0);
        __builtin_amdgcn_global_load_lds(GLB_AS(Bbase + (size_t)row1 * K + k0 + col1), LDS_AS(Bs + c0 * 512 + 512), 16, 0, 0);
        __syncthreads();
        bf16x8 af[4], bfr[4];
#pragma unroll
        for (int f = 0; f < 4; f++) {
            af[f]  = *(const bf16x8*)&As[(wr * 64 + f * 16 + (lane & 15)) * 32 + (lane >> 4) * 8];
            bfr[f] = *(const bf16x8*)&Bs[(wc * 64 + f * 16 + (lane & 15)) * 32 + (lane >> 4) * 8];
        }
#pragma unroll
        for (int fr = 0; fr < 4; fr++)
#pragma unroll
            for (int fc = 0; fc < 4; fc++)
                acc[fr][fc] = __builtin_amdgcn_mfma_f32_16x16x32_bf16(af[fr], bfr[fc], acc[fr][fc], 0, 0, 0);
        __syncthreads();
    }

    const int rg = (lane >> 4) * 4, cl = lane & 15;
#pragma unroll
    for (int fc = 0; fc < 4; fc++) {
        const int col = bn * 128 + wc * 64 + fc * 16 + cl;
        float bv = 0.f;
        if (BIAS) bv = bias[col];
#pragma unroll
        for (int fr = 0; fr < 4; fr++) {
#pragma unroll
            for (int r = 0; r < 4; r++) {
                int rowg = bm * 128 + wr * 64 + fr * 16 + rg + r;
                float v = acc[fr][fc][r] + bv;
                if (RELU) v = fmaxf(v, 0.f);
                if (OUTBF16) ((bf16_t*)Cout)[(size_t)rowg * ldC + col] = (bf16_t)v;
                else         ((float*)Cout)[(size_t)rowg * ldC + col] = v;
            }
        }
    }
}

// ---------------- flash attention ----------------
__device__ __forceinline__ float rowmax16(float v)
{
    v = fmaxf(v, __shfl_xor(v, 1));
    v = fmaxf(v, __shfl_xor(v, 2));
    v = fmaxf(v, __shfl_xor(v, 4));
    v = fmaxf(v, __shfl_xor(v, 8));
    return v;
}
__device__ __forceinline__ float rowsum16(float v)
{
    v += __shfl_xor(v, 1);
    v += __shfl_xor(v, 2);
    v += __shfl_xor(v, 4);
    v += __shfl_xor(v, 8);
    return v;
}

// 4 waves x 32 q-rows = 128 q-rows per block; K-tile = 32.
// Q is pre-scaled by 0.125 at the convert step.
__global__ __launch_bounds__(256)
void flash_kernel(const bf16_t* __restrict__ QKV, const bf16_t* __restrict__ Vt, float* __restrict__ O)
{
    const int tid = threadIdx.x, lane = tid & 63, wid = tid >> 6;
    const int bh = blockIdx.y, b = bh >> 3, h = bh & 7;
    const int qbase = blockIdx.x * 128 + wid * 32;
    __shared__ __align__(16) bf16_t plds[4][16 * 32];
    bf16_t* pw = &plds[wid][0];

    const int l15 = lane & 15, g = lane >> 4;
    const bf16_t* Qbase = QKV + (size_t)(b * 2048) * 1536 + h * 64;
    const bf16_t* Kbase = QKV + (size_t)(b * 2048) * 1536 + 512 + h * 64;
    const bf16_t* Vbase = Vt + (size_t)bh * 64 * 2048;

    bf16x8 qf[2][2];
#pragma unroll
    for (int rb = 0; rb < 2; rb++)
#pragma unroll
        for (int t = 0; t < 2; t++)
            qf[rb][t] = *(const bf16x8*)(Qbase + (size_t)(qbase + rb * 16 + l15) * 1536 + t * 32 + g * 8);

    float m[2][4], l[2][4];
    f32x4 acc[2][4] = {};
#pragma unroll
    for (int rb = 0; rb < 2; rb++)
#pragma unroll
        for (int r = 0; r < 4; r++) { m[rb][r] = -1e30f; l[rb][r] = 0.f; }

    for (int kt = 0; kt < 2048; kt += 32) {
        bf16x8 kf[2][2], vf[4];
#pragma unroll
        for (int c = 0; c < 2; c++)
#pragma unroll
            for (int t = 0; t < 2; t++)
                kf[c][t] = *(const bf16x8*)(Kbase + (size_t)(kt + c * 16 + l15) * 1536 + t * 32 + g * 8);
#pragma unroll
        for (int fc = 0; fc < 4; fc++)
            vf[fc] = *(const bf16x8*)(Vbase + (size_t)(fc * 16 + l15) * 2048 + kt + g * 8);

#pragma unroll
        for (int rb = 0; rb < 2; rb++) {
            f32x4 s0 = {}, s1 = {};
            s0 = __builtin_amdgcn_mfma_f32_16x16x32_bf16(qf[rb][0], kf[0][0], s0, 0, 0, 0);
            s0 = __builtin_amdgcn_mfma_f32_16x16x32_bf16(qf[rb][1], kf[0][1], s0, 0, 0, 0);
            s1 = __builtin_amdgcn_mfma_f32_16x16x32_bf16(qf[rb][0], kf[1][0], s1, 0, 0, 0);
            s1 = __builtin_amdgcn_mfma_f32_16x16x32_bf16(qf[rb][1], kf[1][1], s1, 0, 0, 0);
#pragma unroll
            for (int r = 0; r < 4; r++) {
                float a0 = s0[r], a1 = s1[r];
                float cm = rowmax16(fmaxf(a0, a1));
                float mold = m[rb][r];
                float mnew = fmaxf(mold, cm);
                float fac = __expf(mold - mnew);
                float p0 = __expf(a0 - mnew);
                float p1 = __expf(a1 - mnew);
                float rs = rowsum16(p0 + p1);
                l[rb][r] = l[rb][r] * fac + rs;
                m[rb][r] = mnew;
                acc[rb][0][r] *= fac; acc[rb][1][r] *= fac;
                acc[rb][2][r] *= fac; acc[rb][3][r] *= fac;
                pw[(g * 4 + r) * 32 + l15]      = (bf16_t)p0;
                pw[(g * 4 + r) * 32 + 16 + l15] = (bf16_t)p1;
            }
            // same-wave DS ops are processed in order: writes above visible to this read
            bf16x8 pa = *(const bf16x8*)&pw[l15 * 32 + g * 8];
#pragma unroll
            for (int fc = 0; fc < 4; fc++)
                acc[rb][fc] = __builtin_amdgcn_mfma_f32_16x16x32_bf16(pa, vf[fc], acc[rb][fc], 0, 0, 0);
        }
    }

#pragma unroll
    for (int rb = 0; rb < 2; rb++)
#pragma unroll
        for (int r = 0; r < 4; r++) {
            float inv = 1.f / l[rb][r];
            int rowg = b * 2048 + qbase + rb * 16 + g * 4 + r;
#pragma unroll
            for (int fc = 0; fc < 4; fc++)
                O[(size_t)rowg * 512 + h * 64 + fc * 16 + l15] = acc[rb][fc][r] * inv;
        }
}

// ---------------- fused residual-add + LayerNorm (D=512) ----------------
// a: f32 [row][512]; res: f32 or bf16; outputs: optional f32, optional bf16.
template<bool RESBF>
__global__ __launch_bounds__(128)
void add_ln_kernel(const float* __restrict__ a, const void* __restrict__ res,
                   const float* __restrict__ g, const float* __restrict__ bta,
                   float* outf, bf16_t* outb)
{
    const int row = blockIdx.x, tid = threadIdx.x;
    const float4* a4 = (const float4*)(a + (size_t)row * 512);
    float4 av = a4[tid];
    float r0, r1, r2, r3;
    if (RESBF) {
        bf16x4 rv = ((const bf16x4*)res)[row * 128 + tid];
        r0 = (float)rv[0]; r1 = (float)rv[1]; r2 = (float)rv[2]; r3 = (float)rv[3];
    } else {
        float4 rv = ((const float4*)res)[row * 128 + tid];
        r0 = rv.x; r1 = rv.y; r2 = rv.z; r3 = rv.w;
    }
    float x0 = av.x + r0, x1 = av.y + r1, x2 = av.z + r2, x3 = av.w + r3;
    float s = x0 + x1 + x2 + x3;
    float sq = x0 * x0 + x1 * x1 + x2 * x2 + x3 * x3;
#pragma unroll
    for (int d = 1; d < 64; d <<= 1) { s += __shfl_xor(s, d); sq += __shfl_xor(sq, d); }
    __shared__ float red[2][2];
    const int wid = tid >> 6;
    if ((tid & 63) == 0) { red[wid][0] = s; red[wid][1] = sq; }
    __syncthreads();
    s = red[0][0] + red[1][0];
    sq = red[0][1] + red[1][1];
    float mu = s * (1.f / 512.f);
    float var = sq * (1.f / 512.f) - mu * mu;
    float rstd = rsqrtf(var + 1e-5f);
    const float4* g4 = (const float4*)g;
    const float4* b4 = (const float4*)bta;
    float4 gv = g4[tid], bv = b4[tid];
    float4 y;
    y.x = (x0 - mu) * rstd * gv.x + bv.x;
    y.y = (x1 - mu) * rstd * gv.y + bv.y;
    y.z = (x2 - mu) * rstd * gv.z + bv.z;
    y.w = (x3 - mu) * rstd * gv.w + bv.w;
    if (outf) ((float4*)(outf + (size_t)row * 512))[tid] = y;
    if (outb) {
        bf16x4 o;
        o[0] = (bf16_t)y.x; o[1] = (bf16_t)y.y; o[2] = (bf16_t)y.z; o[3] = (bf16_t)y.w;
        *(bf16x4*)(outb + (size_t)row * 512 + tid * 4) = o;
    }
}

// ---------------- orchestration ----------------
// Workspace arena (29.5 MB high-water; lifetime-safe aliasing):
//   0- 2 MB : W1t   (A->F)
//   2- 4 MB : W2t   (A->G)
//   4- 8 MB : Xb    (A->B)   then out1b (E->H)
//   8-12 MB : Eb    (A->B)
//  12-24 MB : QKVb  (B->D)   then Hb[0:12MB]  (F->G)
//  24-28 MB : Vtb   (C->D)   then Hb[12:16MB] (F->G)
//  28-29.5  : Wqkvt (A->B)
// d_out (8 MB f32) doubles as O (D->E) and FF (G->H, consumed in-place by LN2).
extern "C" void kernel_launch(void* const* d_in, const int* in_sizes, int n_in,
                              void* d_out, int out_size, void* d_ws, size_t ws_size,
                              hipStream_t stream)
{
    const float* inputs = (const float*)d_in[0];
    const float* encx   = (const float*)d_in[1];
    const float* Wq     = (const float*)d_in[2];
    const float* Wk     = (const float*)d_in[3];
    const float* Wv     = (const float*)d_in[4];
    const float* ln1g   = (const float*)d_in[5];
    const float* ln1b   = (const float*)d_in[6];
    const float* W1     = (const float*)d_in[7];
    const float* b1     = (const float*)d_in[8];
    const float* W2     = (const float*)d_in[9];
    const float* b2     = (const float*)d_in[10];
    const float* ln2g   = (const float*)d_in[11];
    const float* ln2b   = (const float*)d_in[12];

    char* ws = (char*)d_ws;
    const size_t MB = 1u << 20;
    bf16_t* W1t   = (bf16_t*)(ws);
    bf16_t* W2t   = (bf16_t*)(ws + 2 * MB);
    bf16_t* Xb    = (bf16_t*)(ws + 4 * MB);
    bf16_t* out1b = (bf16_t*)(ws + 4 * MB);       // aliases Xb (dead after QKV gemm)
    bf16_t* Eb    = (bf16_t*)(ws + 8 * MB);
    bf16_t* QKVb  = (bf16_t*)(ws + 12 * MB);
    bf16_t* Hb    = (bf16_t*)(ws + 12 * MB);      // aliases QKVb+Vtb (dead after flash)
    bf16_t* Vtb   = (bf16_t*)(ws + 24 * MB);
    bf16_t* Wqkvt = (bf16_t*)(ws + 28 * MB);
    float*  Obuf  = (float*)d_out;                // O (dead after ln1)
    float*  FF    = (float*)d_out;                // FF (consumed in-place by ln2)

    // A. converts + weight transposes
    cvt_bf16_kernel<<<2048, 256, 0, stream>>>(inputs, Xb, 2097152, 0.125f); // fold 1/sqrt(64)
    cvt_bf16_kernel<<<2048, 256, 0, stream>>>(encx, Eb, 2097152, 1.0f);
    wtrans_kernel<<<dim3(16, 16), 256, 0, stream>>>(Wq, Wqkvt,              512, 512);
    wtrans_kernel<<<dim3(16, 16), 256, 0, stream>>>(Wk, Wqkvt + 512 * 512,  512, 512);
    wtrans_kernel<<<dim3(16, 16), 256, 0, stream>>>(Wv, Wqkvt + 1024 * 512, 512, 512);
    wtrans_kernel<<<dim3(64, 16), 256, 0, stream>>>(W1, W1t, 512, 2048);
    wtrans_kernel<<<dim3(16, 64), 256, 0, stream>>>(W2, W2t, 2048, 512);
    // B. fused QKV projection: C[4096][1536] (cols 0-511 Q from inputs, 512-1535 K,V from encoder)
    gemm_kernel<true, false, false, true><<<dim3(32, 12), 256, 0, stream>>>(
        Xb, Eb, 4, Wqkvt, nullptr, QKVb, 512, 1536);
    // C. V -> Vt[bh][64][2048]
    vtrans_kernel<<<dim3(32, 16), 256, 0, stream>>>(QKVb, Vtb);
    // D. flash attention -> O (= d_out) f32 [4096][512]
    flash_kernel<<<dim3(16, 16), 256, 0, stream>>>(QKVb, Vtb, Obuf);
    // E. out1 = LN(O + inputs) -> bf16 only
    add_ln_kernel<false><<<4096, 128, 0, stream>>>(Obuf, inputs, ln1g, ln1b, nullptr, out1b);
    // F. H = relu(out1 @ W1 + b1)  [4096][2048] bf16
    gemm_kernel<false, true, true, true><<<dim3(32, 16), 256, 0, stream>>>(
        out1b, nullptr, 0, W1t, b1, Hb, 512, 2048);
    // G. FF = H @ W2 + b2  [4096][512] f32 -> d_out
    gemm_kernel<false, true, false, false><<<dim3(32, 4), 256, 0, stream>>>(
        Hb, nullptr, 0, W2t, b2, FF, 2048, 512);
    // H. final = LN(FF + out1b) -> d_out (in-place, row-local)
    add_ln_kernel<true><<<4096, 128, 0, stream>>>(FF, out1b, ln2g, ln2b, (float*)d_out, nullptr);
}

// Round 4
// 230.095 us; speedup vs baseline: 1.0695x; 1.0695x over previous
//
#include <hip/hip_runtime.h>

typedef __bf16 bf16_t;
typedef __bf16 bf16x8 __attribute__((ext_vector_type(8)));
typedef __bf16 bf16x4 __attribute__((ext_vector_type(4)));
typedef float f32x4 __attribute__((ext_vector_type(4)));

#define GLB_AS(p) ((const __attribute__((address_space(1))) unsigned int*)(p))
#define LDS_AS(p) ((__attribute__((address_space(3))) unsigned int*)(p))

// rows per KV-split = 16 bh * 2048 q = 32768
#define SPLIT_STRIDE 32768

// ---------------- fp32 -> bf16 convert (vectorized), optional scale ----------------
__global__ void cvt_bf16_kernel(const float* __restrict__ in, bf16_t* __restrict__ out, int n, float scale)
{
    int i = (blockIdx.x * blockDim.x + threadIdx.x) * 4;
    if (i >= n) return;
    float4 v = *(const float4*)(in + i);
    bf16x4 o;
    o[0] = (bf16_t)(v.x * scale); o[1] = (bf16_t)(v.y * scale);
    o[2] = (bf16_t)(v.z * scale); o[3] = (bf16_t)(v.w * scale);
    *(bf16x4*)(out + i) = o;
}

// ---------------- weight transpose: in f32 [R][C] -> out bf16 [C][R] ----------------
__global__ void wtrans_kernel(const float* __restrict__ in, bf16_t* __restrict__ out, int R, int C)
{
    __shared__ float tile[32][33];
    const int tid = threadIdx.x;
    const int r0 = blockIdx.y * 32, c0 = blockIdx.x * 32;
#pragma unroll
    for (int j = 0; j < 4; j++) {
        int r = j * 8 + (tid >> 5), c = tid & 31;
        tile[r][c] = in[(size_t)(r0 + r) * C + c0 + c];
    }
    __syncthreads();
#pragma unroll
    for (int j = 0; j < 4; j++) {
        int c = j * 8 + (tid >> 5), r = tid & 31;
        out[(size_t)(c0 + c) * R + r0 + r] = (bf16_t)tile[r][c];
    }
}

// ---------------- V transpose: QKV cols 1024..1535 -> Vt[bh][64][2048] ----------------
__global__ void vtrans_kernel(const bf16_t* __restrict__ qkv, bf16_t* __restrict__ vt)
{
    __shared__ bf16_t t[64][68];
    const int tid = threadIdx.x;
    const int lk0 = blockIdx.x * 64;
    const int bh = blockIdx.y, b = bh >> 3, h = bh & 7;
#pragma unroll
    for (int j = 0; j < 16; j++) {
        int e = j * 256 + tid;
        int lk_i = e >> 6, d = e & 63;
        t[lk_i][d] = qkv[(size_t)(b * 2048 + lk0 + lk_i) * 1536 + 1024 + h * 64 + d];
    }
    __syncthreads();
#pragma unroll
    for (int j = 0; j < 16; j++) {
        int e = j * 256 + tid;
        int d_i = e >> 6, lk = e & 63;
        vt[((size_t)bh * 64 + d_i) * 2048 + lk0 + lk] = t[lk][d_i];
    }
}

// ---------------- GEMM: C[M][N] = A[M][K] @ Bt[N][K]^T ----------------
// BM x 128 tile, BK=32, 256 threads / 4 waves (2x2 wave grid), global_load_lds width 16.
template<int BM, bool SPLITA, bool BIAS, bool RELU, bool OUTBF16>
__global__ __launch_bounds__(256)
void gemm_kernel(const bf16_t* __restrict__ A0, const bf16_t* __restrict__ A1, int nsplit,
                 const bf16_t* __restrict__ Bt, const float* __restrict__ bias,
                 void* __restrict__ Cout, int K, int ldC)
{
    constexpr int FR = BM / 32;  // A-frags per wave (wave owns BM/2 rows)
    __shared__ __align__(16) bf16_t As[BM * 32];
    __shared__ __align__(16) bf16_t Bs[128 * 32];
    const int bm = blockIdx.x, bn = blockIdx.y;
    const bf16_t* A = (!SPLITA || bn < nsplit) ? A0 : A1;
    const int tid = threadIdx.x;
    const int lane = tid & 63;
    const int wid = tid >> 6;
    const int wr = wid >> 1, wc = wid & 1;

    f32x4 acc[FR][4] = {};

    // B staging: 8 chunks of 1 KB, 2 per wave
    const int cb = wid * 2;
    const int lbB0 = cb * 1024 + lane * 16;
    const int rowB0 = lbB0 >> 6, colB0 = (lbB0 & 63) >> 1;
    const int rowB1 = (lbB0 + 1024) >> 6, colB1 = ((lbB0 + 1024) & 63) >> 1;
    // A staging: BM==128 -> 2 chunks/wave, BM==64 -> 1 chunk/wave
    const int lbA0 = (BM == 128 ? cb * 1024 : wid * 1024) + lane * 16;
    const int rowA0 = lbA0 >> 6, colA0 = (lbA0 & 63) >> 1;
    const int rowA1 = (lbA0 + 1024) >> 6, colA1 = ((lbA0 + 1024) & 63) >> 1;

    const bf16_t* Abase = A + (size_t)(bm * BM) * K;
    const bf16_t* Bbase = Bt + (size_t)(bn * 128) * K;

    for (int k0 = 0; k0 < K; k0 += 32) {
        if constexpr (BM == 128) {
            __builtin_amdgcn_global_load_lds(GLB_AS(Abase + (size_t)rowA0 * K + k0 + colA0), LDS_AS(As + cb * 512), 16, 0, 0);
            __builtin_amdgcn_global_load_lds(GLB_AS(Abase + (size_t)rowA1 * K + k0 + colA1), LDS_AS(As + cb * 512 + 512), 16, 0, 0);
        } else {
            __builtin_amdgcn_global_load_lds(GLB_AS(Abase + (size_t)rowA0 * K + k0 + colA0), LDS_AS(As + wid * 512), 16, 0, 0);
        }
        __builtin_amdgcn_global_load_lds(GLB_AS(Bbase + (size_t)rowB0 * K + k0 + colB0), LDS_AS(Bs + cb * 512), 16, 0, 0);
        __builtin_amdgcn_global_load_lds(GLB_AS(Bbase + (size_t)rowB1 * K + k0 + colB1), LDS_AS(Bs + cb * 512 + 512), 16, 0, 0);
        __syncthreads();
        bf16x8 af[FR], bfr[4];
#pragma unroll
        for (int f = 0; f < FR; f++)
            af[f] = *(const bf16x8*)&As[(wr * (BM / 2) + f * 16 + (lane & 15)) * 32 + (lane >> 4) * 8];
#pragma unroll
        for (int f = 0; f < 4; f++)
            bfr[f] = *(const bf16x8*)&Bs[(wc * 64 + f * 16 + (lane & 15)) * 32 + (lane >> 4) * 8];
#pragma unroll
        for (int fr = 0; fr < FR; fr++)
#pragma unroll
            for (int fc = 0; fc < 4; fc++)
                acc[fr][fc] = __builtin_amdgcn_mfma_f32_16x16x32_bf16(af[fr], bfr[fc], acc[fr][fc], 0, 0, 0);
        __syncthreads();
    }

    const int rg = (lane >> 4) * 4, cl = lane & 15;
#pragma unroll
    for (int fc = 0; fc < 4; fc++) {
        const int col = bn * 128 + wc * 64 + fc * 16 + cl;
        float bv = 0.f;
        if (BIAS) bv = bias[col];
#pragma unroll
        for (int fr = 0; fr < FR; fr++) {
#pragma unroll
            for (int r = 0; r < 4; r++) {
                int rowg = bm * BM + wr * (BM / 2) + fr * 16 + rg + r;
                float v = acc[fr][fc][r] + bv;
                if (RELU) v = fmaxf(v, 0.f);
                if (OUTBF16) ((bf16_t*)Cout)[(size_t)rowg * ldC + col] = (bf16_t)v;
                else         ((float*)Cout)[(size_t)rowg * ldC + col] = v;
            }
        }
    }
}

// ---------------- flash attention, KV-split ----------------
__device__ __forceinline__ float rowmax16(float v)
{
    v = fmaxf(v, __shfl_xor(v, 1));
    v = fmaxf(v, __shfl_xor(v, 2));
    v = fmaxf(v, __shfl_xor(v, 4));
    v = fmaxf(v, __shfl_xor(v, 8));
    return v;
}
__device__ __forceinline__ float rowsum16(float v)
{
    v += __shfl_xor(v, 1);
    v += __shfl_xor(v, 2);
    v += __shfl_xor(v, 4);
    v += __shfl_xor(v, 8);
    return v;
}

// grid (32 qblocks, 16 bh, 2 kv-splits); 4 waves x 16 q-rows = 64 q-rows/block.
// Each block covers kt in [split*1024, split*1024+1024).
// Writes normalized partial O (bf16) + per-row (m,l) f32.
// Q pre-scaled by 0.125 at the convert step.
__global__ __launch_bounds__(256)
void flash_kernel(const bf16_t* __restrict__ QKV, const bf16_t* __restrict__ Vt,
                  bf16_t* __restrict__ Opart, float2* __restrict__ ml)
{
    const int tid = threadIdx.x, lane = tid & 63, wid = tid >> 6;
    const int bh = blockIdx.y, b = bh >> 3, h = bh & 7;
    const int split = blockIdx.z;
    const int qbase = blockIdx.x * 64 + wid * 16;   // q-row base of this wave (within bh)
    __shared__ __align__(16) bf16_t plds[4][16 * 32];
    bf16_t* pw = &plds[wid][0];

    const int l15 = lane & 15, g = lane >> 4;
    const bf16_t* Qbase = QKV + (size_t)(b * 2048) * 1536 + h * 64;
    const bf16_t* Kbase = QKV + (size_t)(b * 2048) * 1536 + 512 + h * 64;
    const bf16_t* Vbase = Vt + (size_t)bh * 64 * 2048;

    bf16x8 qf[2];
#pragma unroll
    for (int t = 0; t < 2; t++)
        qf[t] = *(const bf16x8*)(Qbase + (size_t)(qbase + l15) * 1536 + t * 32 + g * 8);

    float m[4], l[4];
    f32x4 acc[4] = {};
#pragma unroll
    for (int r = 0; r < 4; r++) { m[r] = -1e30f; l[r] = 0.f; }

    const int kv0 = split * 1024;
    for (int kt = kv0; kt < kv0 + 1024; kt += 32) {
        bf16x8 kf[2][2], vf[4];
#pragma unroll
        for (int c = 0; c < 2; c++)
#pragma unroll
            for (int t = 0; t < 2; t++)
                kf[c][t] = *(const bf16x8*)(Kbase + (size_t)(kt + c * 16 + l15) * 1536 + t * 32 + g * 8);
#pragma unroll
        for (int fc = 0; fc < 4; fc++)
            vf[fc] = *(const bf16x8*)(Vbase + (size_t)(fc * 16 + l15) * 2048 + kt + g * 8);

        f32x4 s0 = {}, s1 = {};
        s0 = __builtin_amdgcn_mfma_f32_16x16x32_bf16(qf[0], kf[0][0], s0, 0, 0, 0);
        s0 = __builtin_amdgcn_mfma_f32_16x16x32_bf16(qf[1], kf[0][1], s0, 0, 0, 0);
        s1 = __builtin_amdgcn_mfma_f32_16x16x32_bf16(qf[0], kf[1][0], s1, 0, 0, 0);
        s1 = __builtin_amdgcn_mfma_f32_16x16x32_bf16(qf[1], kf[1][1], s1, 0, 0, 0);
#pragma unroll
        for (int r = 0; r < 4; r++) {
            float a0 = s0[r], a1 = s1[r];
            float cm = rowmax16(fmaxf(a0, a1));
            float mold = m[r];
            float mnew = fmaxf(mold, cm);
            float fac = __expf(mold - mnew);
            float p0 = __expf(a0 - mnew);
            float p1 = __expf(a1 - mnew);
            float rs = rowsum16(p0 + p1);
            l[r] = l[r] * fac + rs;
            m[r] = mnew;
            acc[0][r] *= fac; acc[1][r] *= fac;
            acc[2][r] *= fac; acc[3][r] *= fac;
            pw[(g * 4 + r) * 32 + l15]      = (bf16_t)p0;
            pw[(g * 4 + r) * 32 + 16 + l15] = (bf16_t)p1;
        }
        // same-wave DS ops are processed in order: writes above visible to this read
        bf16x8 pa = *(const bf16x8*)&pw[l15 * 32 + g * 8];
#pragma unroll
        for (int fc = 0; fc < 4; fc++)
            acc[fc] = __builtin_amdgcn_mfma_f32_16x16x32_bf16(pa, vf[fc], acc[fc], 0, 0, 0);
    }

    // write normalized bf16 partial + (m,l)
#pragma unroll
    for (int r = 0; r < 4; r++) {
        const int qrow = qbase + g * 4 + r;
        const size_t prow = (size_t)split * SPLIT_STRIDE + (size_t)bh * 2048 + qrow;
        float inv = 1.f / l[r];
#pragma unroll
        for (int fc = 0; fc < 4; fc++)
            Opart[prow * 64 + fc * 16 + l15] = (bf16_t)(acc[fc][r] * inv);
        if (l15 == 0) ml[prow] = make_float2(m[r], l[r]);
    }
}

// ---------------- combine 2 KV-split partials -> O f32 [4096][512] ----------------
// 32768 rows x 64 dims = 2,097,152 threads = 8192 blocks x 256.
__global__ __launch_bounds__(256)
void combine_kernel(const bf16_t* __restrict__ Opart, const float2* __restrict__ ml,
                    float* __restrict__ O)
{
    int t = blockIdx.x * 256 + threadIdx.x;
    int dim = t & 63;
    int row = t >> 6;                          // bh*2048 + qrow, < 32768
    int bh = row >> 11, qrow = row & 2047;
    float2 ml0 = ml[row];
    float2 ml1 = ml[SPLIT_STRIDE + row];
    float M = fmaxf(ml0.x, ml1.x);
    float w0 = ml0.y * __expf(ml0.x - M);
    float w1 = ml1.y * __expf(ml1.x - M);
    float o = (w0 * (float)Opart[(size_t)row * 64 + dim]
             + w1 * (float)Opart[(size_t)(SPLIT_STRIDE + row) * 64 + dim]) / (w0 + w1);
    int b = bh >> 3, h = bh & 7;
    O[((size_t)(b * 2048 + qrow)) * 512 + h * 64 + dim] = o;
}

// ---------------- fused residual-add + LayerNorm (D=512) ----------------
template<bool RESBF>
__global__ __launch_bounds__(128)
void add_ln_kernel(const float* __restrict__ a, const void* __restrict__ res,
                   const float* __restrict__ g, const float* __restrict__ bta,
                   float* outf, bf16_t* outb)
{
    const int row = blockIdx.x, tid = threadIdx.x;
    const float4* a4 = (const float4*)(a + (size_t)row * 512);
    float4 av = a4[tid];
    float r0, r1, r2, r3;
    if (RESBF) {
        bf16x4 rv = ((const bf16x4*)res)[row * 128 + tid];
        r0 = (float)rv[0]; r1 = (float)rv[1]; r2 = (float)rv[2]; r3 = (float)rv[3];
    } else {
        float4 rv = ((const float4*)res)[row * 128 + tid];
        r0 = rv.x; r1 = rv.y; r2 = rv.z; r3 = rv.w;
    }
    float x0 = av.x + r0, x1 = av.y + r1, x2 = av.z + r2, x3 = av.w + r3;
    float s = x0 + x1 + x2 + x3;
    float sq = x0 * x0 + x1 * x1 + x2 * x2 + x3 * x3;
#pragma unroll
    for (int d = 1; d < 64; d <<= 1) { s += __shfl_xor(s, d); sq += __shfl_xor(sq, d); }
    __shared__ float red[2][2];
    const int wid = tid >> 6;
    if ((tid & 63) == 0) { red[wid][0] = s; red[wid][1] = sq; }
    __syncthreads();
    s = red[0][0] + red[1][0];
    sq = red[0][1] + red[1][1];
    float mu = s * (1.f / 512.f);
    float var = sq * (1.f / 512.f) - mu * mu;
    float rstd = rsqrtf(var + 1e-5f);
    const float4* g4 = (const float4*)g;
    const float4* b4 = (const float4*)bta;
    float4 gv = g4[tid], bv = b4[tid];
    float4 y;
    y.x = (x0 - mu) * rstd * gv.x + bv.x;
    y.y = (x1 - mu) * rstd * gv.y + bv.y;
    y.z = (x2 - mu) * rstd * gv.z + bv.z;
    y.w = (x3 - mu) * rstd * gv.w + bv.w;
    if (outf) ((float4*)(outf + (size_t)row * 512))[tid] = y;
    if (outb) {
        bf16x4 o;
        o[0] = (bf16_t)y.x; o[1] = (bf16_t)y.y; o[2] = (bf16_t)y.z; o[3] = (bf16_t)y.w;
        *(bf16x4*)(outb + (size_t)row * 512 + tid * 4) = o;
    }
}

// ---------------- orchestration ----------------
// Workspace arena (29.5 MB high-water; lifetime-safe aliasing):
//   0- 2 MB : W1t    (A->F)
//   2- 4 MB : W2t    (A->G)
//   4-12 MB : Xb+Eb  (A->B)  then Opart (8 MB: 2 splits x 32768 rows x 64 bf16) (D->D2)
//             out1b (4 MB) aliases 4-8 MB after combine (E->H)
//  12-24 MB : QKVb   (B->D)  then Hb[0:12MB]   (F->G)
//  24-28 MB : Vtb    (C->D)  then Hb[12:16MB]  (F->G)
//  28-29.5  : Wqkvt  (A->B)  then ml (512 KB)  (D->D2)
// d_out (8 MB f32) doubles as O (D2->E) and FF (G->H, consumed in-place by LN2).
extern "C" void kernel_launch(void* const* d_in, const int* in_sizes, int n_in,
                              void* d_out, int out_size, void* d_ws, size_t ws_size,
                              hipStream_t stream)
{
    const float* inputs = (const float*)d_in[0];
    const float* encx   = (const float*)d_in[1];
    const float* Wq     = (const float*)d_in[2];
    const float* Wk     = (const float*)d_in[3];
    const float* Wv     = (const float*)d_in[4];
    const float* ln1g   = (const float*)d_in[5];
    const float* ln1b   = (const float*)d_in[6];
    const float* W1     = (const float*)d_in[7];
    const float* b1     = (const float*)d_in[8];
    const float* W2     = (const float*)d_in[9];
    const float* b2     = (const float*)d_in[10];
    const float* ln2g   = (const float*)d_in[11];
    const float* ln2b   = (const float*)d_in[12];

    char* ws = (char*)d_ws;
    const size_t MB = 1u << 20;
    bf16_t* W1t   = (bf16_t*)(ws);
    bf16_t* W2t   = (bf16_t*)(ws + 2 * MB);
    bf16_t* Xb    = (bf16_t*)(ws + 4 * MB);
    bf16_t* Opart = (bf16_t*)(ws + 4 * MB);       // 8 MB, aliases Xb+Eb (dead after QKV gemm)
    bf16_t* out1b = (bf16_t*)(ws + 4 * MB);       // 4 MB, aliases Opart[0:4] (dead after combine)
    bf16_t* Eb    = (bf16_t*)(ws + 8 * MB);
    bf16_t* QKVb  = (bf16_t*)(ws + 12 * MB);
    bf16_t* Hb    = (bf16_t*)(ws + 12 * MB);      // aliases QKVb+Vtb (dead after flash)
    bf16_t* Vtb   = (bf16_t*)(ws + 24 * MB);
    bf16_t* Wqkvt = (bf16_t*)(ws + 28 * MB);
    float2* mlbuf = (float2*)(ws + 28 * MB);      // 512 KB, aliases Wqkvt (dead after QKV gemm)
    float*  Obuf  = (float*)d_out;                // O (dead after ln1)
    float*  FF    = (float*)d_out;                // FF (consumed in-place by ln2)

    // A. converts + weight transposes
    cvt_bf16_kernel<<<2048, 256, 0, stream>>>(inputs, Xb, 2097152, 0.125f); // fold 1/sqrt(64)
    cvt_bf16_kernel<<<2048, 256, 0, stream>>>(encx, Eb, 2097152, 1.0f);
    wtrans_kernel<<<dim3(16, 16), 256, 0, stream>>>(Wq, Wqkvt,              512, 512);
    wtrans_kernel<<<dim3(16, 16), 256, 0, stream>>>(Wk, Wqkvt + 512 * 512,  512, 512);
    wtrans_kernel<<<dim3(16, 16), 256, 0, stream>>>(Wv, Wqkvt + 1024 * 512, 512, 512);
    wtrans_kernel<<<dim3(64, 16), 256, 0, stream>>>(W1, W1t, 512, 2048);
    wtrans_kernel<<<dim3(16, 64), 256, 0, stream>>>(W2, W2t, 2048, 512);
    // B. fused QKV projection: C[4096][1536] (cols 0-511 Q from inputs, 512-1535 K,V from encoder)
    gemm_kernel<64, true, false, false, true><<<dim3(64, 12), 256, 0, stream>>>(
        Xb, Eb, 4, Wqkvt, nullptr, QKVb, 512, 1536);
    // C. V -> Vt[bh][64][2048]
    vtrans_kernel<<<dim3(32, 16), 256, 0, stream>>>(QKVb, Vtb);
    // D. flash attention (kv-split 2) -> bf16 partials + (m,l)
    flash_kernel<<<dim3(32, 16, 2), 256, 0, stream>>>(QKVb, Vtb, Opart, mlbuf);
    // D2. combine partials -> O (= d_out) f32 [4096][512]
    combine_kernel<<<8192, 256, 0, stream>>>(Opart, mlbuf, Obuf);
    // E. out1 = LN(O + inputs) -> bf16 only
    add_ln_kernel<false><<<4096, 128, 0, stream>>>(Obuf, inputs, ln1g, ln1b, nullptr, out1b);
    // F. H = relu(out1 @ W1 + b1)  [4096][2048] bf16
    gemm_kernel<128, false, true, true, true><<<dim3(32, 16), 256, 0, stream>>>(
        out1b, nullptr, 0, W1t, b1, Hb, 512, 2048);
    // G. FF = H @ W2 + b2  [4096][512] f32 -> d_out
    gemm_kernel<64, false, true, false, false><<<dim3(64, 4), 256, 0, stream>>>(
        Hb, nullptr, 0, W2t, b2, FF, 2048, 512);
    // H. final = LN(FF + out1b) -> d_out (in-place, row-local)
    add_ln_kernel<true><<<4096, 128, 0, stream>>>(FF, out1b, ln2g, ln2b, (float*)d_out, nullptr);
}

// Round 5
// 227.648 us; speedup vs baseline: 1.0810x; 1.0107x over previous
//
#include <hip/hip_runtime.h>

typedef __bf16 bf16_t;
typedef __bf16 bf16x8 __attribute__((ext_vector_type(8)));
typedef __bf16 bf16x4 __attribute__((ext_vector_type(4)));
typedef float f32x4 __attribute__((ext_vector_type(4)));

#define GLB_AS(p) ((const __attribute__((address_space(1))) unsigned int*)(p))
#define LDS_AS(p) ((__attribute__((address_space(3))) unsigned int*)(p))

// rows per KV-split = 16 bh * 2048 q = 32768
#define SPLIT_STRIDE 32768
// P-tile LDS row stride (64 + 2 pad) -> row stride 132B = 33 banks, breaks row bank-alignment
#define PLD 66

// ---------------- fp32 -> bf16 convert (vectorized), optional scale ----------------
__global__ void cvt_bf16_kernel(const float* __restrict__ in, bf16_t* __restrict__ out, int n, float scale)
{
    int i = (blockIdx.x * blockDim.x + threadIdx.x) * 4;
    if (i >= n) return;
    float4 v = *(const float4*)(in + i);
    bf16x4 o;
    o[0] = (bf16_t)(v.x * scale); o[1] = (bf16_t)(v.y * scale);
    o[2] = (bf16_t)(v.z * scale); o[3] = (bf16_t)(v.w * scale);
    *(bf16x4*)(out + i) = o;
}

// ---------------- weight transpose: in f32 [R][C] -> out bf16 [C][R] ----------------
__global__ void wtrans_kernel(const float* __restrict__ in, bf16_t* __restrict__ out, int R, int C)
{
    __shared__ float tile[32][33];
    const int tid = threadIdx.x;
    const int r0 = blockIdx.y * 32, c0 = blockIdx.x * 32;
#pragma unroll
    for (int j = 0; j < 4; j++) {
        int r = j * 8 + (tid >> 5), c = tid & 31;
        tile[r][c] = in[(size_t)(r0 + r) * C + c0 + c];
    }
    __syncthreads();
#pragma unroll
    for (int j = 0; j < 4; j++) {
        int c = j * 8 + (tid >> 5), r = tid & 31;
        out[(size_t)(c0 + c) * R + r0 + r] = (bf16_t)tile[r][c];
    }
}

// ---------------- V transpose: QKV cols 1024..1535 -> Vt[bh][64][2048] ----------------
__global__ void vtrans_kernel(const bf16_t* __restrict__ qkv, bf16_t* __restrict__ vt)
{
    __shared__ bf16_t t[64][68];
    const int tid = threadIdx.x;
    const int lk0 = blockIdx.x * 64;
    const int bh = blockIdx.y, b = bh >> 3, h = bh & 7;
#pragma unroll
    for (int j = 0; j < 16; j++) {
        int e = j * 256 + tid;
        int lk_i = e >> 6, d = e & 63;
        t[lk_i][d] = qkv[(size_t)(b * 2048 + lk0 + lk_i) * 1536 + 1024 + h * 64 + d];
    }
    __syncthreads();
#pragma unroll
    for (int j = 0; j < 16; j++) {
        int e = j * 256 + tid;
        int d_i = e >> 6, lk = e & 63;
        vt[((size_t)bh * 64 + d_i) * 2048 + lk0 + lk] = t[lk][d_i];
    }
}

// ---------------- GEMM: C[M][N] = A[M][K] @ Bt[N][K]^T ----------------
// BM x 128 tile, BK=32, 256 threads / 4 waves (2x2 wave grid), global_load_lds width 16.
template<int BM, bool SPLITA, bool BIAS, bool RELU, bool OUTBF16>
__global__ __launch_bounds__(256)
void gemm_kernel(const bf16_t* __restrict__ A0, const bf16_t* __restrict__ A1, int nsplit,
                 const bf16_t* __restrict__ Bt, const float* __restrict__ bias,
                 void* __restrict__ Cout, int K, int ldC)
{
    constexpr int FR = BM / 32;  // A-frags per wave (wave owns BM/2 rows)
    __shared__ __align__(16) bf16_t As[BM * 32];
    __shared__ __align__(16) bf16_t Bs[128 * 32];
    const int bm = blockIdx.x, bn = blockIdx.y;
    const bf16_t* A = (!SPLITA || bn < nsplit) ? A0 : A1;
    const int tid = threadIdx.x;
    const int lane = tid & 63;
    const int wid = tid >> 6;
    const int wr = wid >> 1, wc = wid & 1;

    f32x4 acc[FR][4] = {};

    // B staging: 8 chunks of 1 KB, 2 per wave
    const int cb = wid * 2;
    const int lbB0 = cb * 1024 + lane * 16;
    const int rowB0 = lbB0 >> 6, colB0 = (lbB0 & 63) >> 1;
    const int rowB1 = (lbB0 + 1024) >> 6, colB1 = ((lbB0 + 1024) & 63) >> 1;
    // A staging: BM==128 -> 2 chunks/wave, BM==64 -> 1 chunk/wave
    const int lbA0 = (BM == 128 ? cb * 1024 : wid * 1024) + lane * 16;
    const int rowA0 = lbA0 >> 6, colA0 = (lbA0 & 63) >> 1;
    const int rowA1 = (lbA0 + 1024) >> 6, colA1 = ((lbA0 + 1024) & 63) >> 1;

    const bf16_t* Abase = A + (size_t)(bm * BM) * K;
    const bf16_t* Bbase = Bt + (size_t)(bn * 128) * K;

    for (int k0 = 0; k0 < K; k0 += 32) {
        if constexpr (BM == 128) {
            __builtin_amdgcn_global_load_lds(GLB_AS(Abase + (size_t)rowA0 * K + k0 + colA0), LDS_AS(As + cb * 512), 16, 0, 0);
            __builtin_amdgcn_global_load_lds(GLB_AS(Abase + (size_t)rowA1 * K + k0 + colA1), LDS_AS(As + cb * 512 + 512), 16, 0, 0);
        } else {
            __builtin_amdgcn_global_load_lds(GLB_AS(Abase + (size_t)rowA0 * K + k0 + colA0), LDS_AS(As + wid * 512), 16, 0, 0);
        }
        __builtin_amdgcn_global_load_lds(GLB_AS(Bbase + (size_t)rowB0 * K + k0 + colB0), LDS_AS(Bs + cb * 512), 16, 0, 0);
        __builtin_amdgcn_global_load_lds(GLB_AS(Bbase + (size_t)rowB1 * K + k0 + colB1), LDS_AS(Bs + cb * 512 + 512), 16, 0, 0);
        __syncthreads();
        bf16x8 af[FR], bfr[4];
#pragma unroll
        for (int f = 0; f < FR; f++)
            af[f] = *(const bf16x8*)&As[(wr * (BM / 2) + f * 16 + (lane & 15)) * 32 + (lane >> 4) * 8];
#pragma unroll
        for (int f = 0; f < 4; f++)
            bfr[f] = *(const bf16x8*)&Bs[(wc * 64 + f * 16 + (lane & 15)) * 32 + (lane >> 4) * 8];
#pragma unroll
        for (int fr = 0; fr < FR; fr++)
#pragma unroll
            for (int fc = 0; fc < 4; fc++)
                acc[fr][fc] = __builtin_amdgcn_mfma_f32_16x16x32_bf16(af[fr], bfr[fc], acc[fr][fc], 0, 0, 0);
        __syncthreads();
    }

    const int rg = (lane >> 4) * 4, cl = lane & 15;
#pragma unroll
    for (int fc = 0; fc < 4; fc++) {
        const int col = bn * 128 + wc * 64 + fc * 16 + cl;
        float bv = 0.f;
        if (BIAS) bv = bias[col];
#pragma unroll
        for (int fr = 0; fr < FR; fr++) {
#pragma unroll
            for (int r = 0; r < 4; r++) {
                int rowg = bm * BM + wr * (BM / 2) + fr * 16 + rg + r;
                float v = acc[fr][fc][r] + bv;
                if (RELU) v = fmaxf(v, 0.f);
                if (OUTBF16) ((bf16_t*)Cout)[(size_t)rowg * ldC + col] = (bf16_t)v;
                else         ((float*)Cout)[(size_t)rowg * ldC + col] = v;
            }
        }
    }
}

// ---------------- flash attention, KV-split, KVBLK=64, exp2-domain ----------------
__device__ __forceinline__ float rowmax16(float v)
{
    v = fmaxf(v, __shfl_xor(v, 1));
    v = fmaxf(v, __shfl_xor(v, 2));
    v = fmaxf(v, __shfl_xor(v, 4));
    v = fmaxf(v, __shfl_xor(v, 8));
    return v;
}

// grid (32 qblocks, 16 bh, 2 kv-splits); 4 waves x 16 q-rows = 64 q-rows/block.
// KVBLK = 64 per iteration; 16 iterations cover this split's 1024 kv rows.
// Q pre-scaled by 0.125*log2(e) at the convert step -> scores in log2 units,
// all exps are raw v_exp_f32; m tracked in log2 units; row-sum computed by an
// extra MFMA against an all-ones B fragment (no cross-lane sum reduce).
__global__ __launch_bounds__(256)
void flash_kernel(const bf16_t* __restrict__ QKV, const bf16_t* __restrict__ Vt,
                  bf16_t* __restrict__ Opart, float2* __restrict__ ml)
{
    const int tid = threadIdx.x, lane = tid & 63, wid = tid >> 6;
    const int bh = blockIdx.y, b = bh >> 3, h = bh & 7;
    const int split = blockIdx.z;
    const int qbase = blockIdx.x * 64 + wid * 16;   // q-row base of this wave (within bh)
    __shared__ __align__(16) bf16_t plds[4][16 * PLD];
    bf16_t* pw = &plds[wid][0];

    const int l15 = lane & 15, g = lane >> 4;
    const bf16_t* Qbase = QKV + (size_t)(b * 2048) * 1536 + h * 64;
    const bf16_t* Kbase = QKV + (size_t)(b * 2048) * 1536 + 512 + h * 64;
    const bf16_t* Vbase = Vt + (size_t)bh * 64 * 2048;

    bf16x8 qf[2];
#pragma unroll
    for (int t = 0; t < 2; t++)
        qf[t] = *(const bf16x8*)(Qbase + (size_t)(qbase + l15) * 1536 + t * 32 + g * 8);

    bf16x8 ones;
#pragma unroll
    for (int e = 0; e < 8; e++) ones[e] = (bf16_t)1.0f;

    float m[4];
    f32x4 acc[4] = {};
    f32x4 accs = {};
#pragma unroll
    for (int r = 0; r < 4; r++) m[r] = -1e30f;

    const int kv0 = split * 1024;
    for (int kt = kv0; kt < kv0 + 1024; kt += 64) {
        bf16x8 kf[4][2], vf[2][4];
#pragma unroll
        for (int c = 0; c < 4; c++)
#pragma unroll
            for (int t = 0; t < 2; t++)
                kf[c][t] = *(const bf16x8*)(Kbase + (size_t)(kt + c * 16 + l15) * 1536 + t * 32 + g * 8);
#pragma unroll
        for (int ks = 0; ks < 2; ks++)
#pragma unroll
            for (int fc = 0; fc < 4; fc++)
                vf[ks][fc] = *(const bf16x8*)(Vbase + (size_t)(fc * 16 + l15) * 2048 + kt + ks * 32 + g * 8);

        f32x4 s[4] = {};
        __builtin_amdgcn_s_setprio(1);
#pragma unroll
        for (int c = 0; c < 4; c++) {
            s[c] = __builtin_amdgcn_mfma_f32_16x16x32_bf16(qf[0], kf[c][0], s[c], 0, 0, 0);
            s[c] = __builtin_amdgcn_mfma_f32_16x16x32_bf16(qf[1], kf[c][1], s[c], 0, 0, 0);
        }
        __builtin_amdgcn_s_setprio(0);

#pragma unroll
        for (int r = 0; r < 4; r++) {
            float a0 = s[0][r], a1 = s[1][r], a2 = s[2][r], a3 = s[3][r];
            float cm = fmaxf(fmaxf(a0, a1), fmaxf(a2, a3));
            cm = rowmax16(cm);                       // 4 shfl over the row's 16 lanes
            float mold = m[r];
            float mnew = fmaxf(mold, cm);
            float fac = __builtin_amdgcn_exp2f(mold - mnew);
            m[r] = mnew;
            acc[0][r] *= fac; acc[1][r] *= fac;
            acc[2][r] *= fac; acc[3][r] *= fac;
            accs[r] *= fac;
            const int row = g * 4 + r;
            pw[row * PLD +      l15] = (bf16_t)__builtin_amdgcn_exp2f(a0 - mnew);
            pw[row * PLD + 16 + l15] = (bf16_t)__builtin_amdgcn_exp2f(a1 - mnew);
            pw[row * PLD + 32 + l15] = (bf16_t)__builtin_amdgcn_exp2f(a2 - mnew);
            pw[row * PLD + 48 + l15] = (bf16_t)__builtin_amdgcn_exp2f(a3 - mnew);
        }

        // same-wave DS ops are processed in order: writes above visible to reads below
        __builtin_amdgcn_s_setprio(1);
#pragma unroll
        for (int ks = 0; ks < 2; ks++) {
            bf16x8 pa = *(const bf16x8*)&pw[l15 * PLD + ks * 32 + g * 8];
#pragma unroll
            for (int fc = 0; fc < 4; fc++)
                acc[fc] = __builtin_amdgcn_mfma_f32_16x16x32_bf16(pa, vf[ks][fc], acc[fc], 0, 0, 0);
            accs = __builtin_amdgcn_mfma_f32_16x16x32_bf16(pa, ones, accs, 0, 0, 0);
        }
        __builtin_amdgcn_s_setprio(0);
    }

    // write normalized bf16 partial + (m, l)  (l = accs row-sum, uniform across cols)
#pragma unroll
    for (int r = 0; r < 4; r++) {
        const int qrow = qbase + g * 4 + r;
        const size_t prow = (size_t)split * SPLIT_STRIDE + (size_t)bh * 2048 + qrow;
        float inv = 1.f / accs[r];
#pragma unroll
        for (int fc = 0; fc < 4; fc++)
            Opart[prow * 64 + fc * 16 + l15] = (bf16_t)(acc[fc][r] * inv);
        if (l15 == 0) ml[prow] = make_float2(m[r], accs[r]);
    }
}

// ---------------- combine 2 KV-split partials -> O f32 [4096][512] ----------------
// 32768 rows x 64 dims = 2,097,152 threads = 8192 blocks x 256. m is in log2 units.
__global__ __launch_bounds__(256)
void combine_kernel(const bf16_t* __restrict__ Opart, const float2* __restrict__ ml,
                    float* __restrict__ O)
{
    int t = blockIdx.x * 256 + threadIdx.x;
    int dim = t & 63;
    int row = t >> 6;                          // bh*2048 + qrow, < 32768
    int bh = row >> 11, qrow = row & 2047;
    float2 ml0 = ml[row];
    float2 ml1 = ml[SPLIT_STRIDE + row];
    float M = fmaxf(ml0.x, ml1.x);
    float w0 = ml0.y * __builtin_amdgcn_exp2f(ml0.x - M);
    float w1 = ml1.y * __builtin_amdgcn_exp2f(ml1.x - M);
    float o = (w0 * (float)Opart[(size_t)row * 64 + dim]
             + w1 * (float)Opart[(size_t)(SPLIT_STRIDE + row) * 64 + dim]) / (w0 + w1);
    int b = bh >> 3, h = bh & 7;
    O[((size_t)(b * 2048 + qrow)) * 512 + h * 64 + dim] = o;
}

// ---------------- fused residual-add + LayerNorm (D=512) ----------------
template<bool RESBF>
__global__ __launch_bounds__(128)
void add_ln_kernel(const float* __restrict__ a, const void* __restrict__ res,
                   const float* __restrict__ g, const float* __restrict__ bta,
                   float* outf, bf16_t* outb)
{
    const int row = blockIdx.x, tid = threadIdx.x;
    const float4* a4 = (const float4*)(a + (size_t)row * 512);
    float4 av = a4[tid];
    float r0, r1, r2, r3;
    if (RESBF) {
        bf16x4 rv = ((const bf16x4*)res)[row * 128 + tid];
        r0 = (float)rv[0]; r1 = (float)rv[1]; r2 = (float)rv[2]; r3 = (float)rv[3];
    } else {
        float4 rv = ((const float4*)res)[row * 128 + tid];
        r0 = rv.x; r1 = rv.y; r2 = rv.z; r3 = rv.w;
    }
    float x0 = av.x + r0, x1 = av.y + r1, x2 = av.z + r2, x3 = av.w + r3;
    float s = x0 + x1 + x2 + x3;
    float sq = x0 * x0 + x1 * x1 + x2 * x2 + x3 * x3;
#pragma unroll
    for (int d = 1; d < 64; d <<= 1) { s += __shfl_xor(s, d); sq += __shfl_xor(sq, d); }
    __shared__ float red[2][2];
    const int wid = tid >> 6;
    if ((tid & 63) == 0) { red[wid][0] = s; red[wid][1] = sq; }
    __syncthreads();
    s = red[0][0] + red[1][0];
    sq = red[0][1] + red[1][1];
    float mu = s * (1.f / 512.f);
    float var = sq * (1.f / 512.f) - mu * mu;
    float rstd = rsqrtf(var + 1e-5f);
    const float4* g4 = (const float4*)g;
    const float4* b4 = (const float4*)bta;
    float4 gv = g4[tid], bv = b4[tid];
    float4 y;
    y.x = (x0 - mu) * rstd * gv.x + bv.x;
    y.y = (x1 - mu) * rstd * gv.y + bv.y;
    y.z = (x2 - mu) * rstd * gv.z + bv.z;
    y.w = (x3 - mu) * rstd * gv.w + bv.w;
    if (outf) ((float4*)(outf + (size_t)row * 512))[tid] = y;
    if (outb) {
        bf16x4 o;
        o[0] = (bf16_t)y.x; o[1] = (bf16_t)y.y; o[2] = (bf16_t)y.z; o[3] = (bf16_t)y.w;
        *(bf16x4*)(outb + (size_t)row * 512 + tid * 4) = o;
    }
}

// ---------------- orchestration ----------------
// Workspace arena (29.5 MB high-water; lifetime-safe aliasing):
//   0- 2 MB : W1t    (A->F)
//   2- 4 MB : W2t    (A->G)
//   4-12 MB : Xb+Eb  (A->B)  then Opart (8 MB: 2 splits x 32768 rows x 64 bf16) (D->D2)
//             out1b (4 MB) aliases 4-8 MB after combine (E->H)
//  12-24 MB : QKVb   (B->D)  then Hb[0:12MB]   (F->G)
//  24-28 MB : Vtb    (C->D)  then Hb[12:16MB]  (F->G)
//  28-29.5  : Wqkvt  (A->B)  then ml (512 KB)  (D->D2)
// d_out (8 MB f32) doubles as O (D2->E) and FF (G->H, consumed in-place by LN2).
extern "C" void kernel_launch(void* const* d_in, const int* in_sizes, int n_in,
                              void* d_out, int out_size, void* d_ws, size_t ws_size,
                              hipStream_t stream)
{
    const float* inputs = (const float*)d_in[0];
    const float* encx   = (const float*)d_in[1];
    const float* Wq     = (const float*)d_in[2];
    const float* Wk     = (const float*)d_in[3];
    const float* Wv     = (const float*)d_in[4];
    const float* ln1g   = (const float*)d_in[5];
    const float* ln1b   = (const float*)d_in[6];
    const float* W1     = (const float*)d_in[7];
    const float* b1     = (const float*)d_in[8];
    const float* W2     = (const float*)d_in[9];
    const float* b2     = (const float*)d_in[10];
    const float* ln2g   = (const float*)d_in[11];
    const float* ln2b   = (const float*)d_in[12];

    char* ws = (char*)d_ws;
    const size_t MB = 1u << 20;
    bf16_t* W1t   = (bf16_t*)(ws);
    bf16_t* W2t   = (bf16_t*)(ws + 2 * MB);
    bf16_t* Xb    = (bf16_t*)(ws + 4 * MB);
    bf16_t* Opart = (bf16_t*)(ws + 4 * MB);       // 8 MB, aliases Xb+Eb (dead after QKV gemm)
    bf16_t* out1b = (bf16_t*)(ws + 4 * MB);       // 4 MB, aliases Opart[0:4] (dead after combine)
    bf16_t* Eb    = (bf16_t*)(ws + 8 * MB);
    bf16_t* QKVb  = (bf16_t*)(ws + 12 * MB);
    bf16_t* Hb    = (bf16_t*)(ws + 12 * MB);      // aliases QKVb+Vtb (dead after flash)
    bf16_t* Vtb   = (bf16_t*)(ws + 24 * MB);
    bf16_t* Wqkvt = (bf16_t*)(ws + 28 * MB);
    float2* mlbuf = (float2*)(ws + 28 * MB);      // 512 KB, aliases Wqkvt (dead after QKV gemm)
    float*  Obuf  = (float*)d_out;                // O (dead after ln1)
    float*  FF    = (float*)d_out;                // FF (consumed in-place by ln2)

    // A. converts + weight transposes.  Q path folds 0.125 * log2(e) (exp2 domain).
    cvt_bf16_kernel<<<2048, 256, 0, stream>>>(inputs, Xb, 2097152, 0.125f * 1.44269504f);
    cvt_bf16_kernel<<<2048, 256, 0, stream>>>(encx, Eb, 2097152, 1.0f);
    wtrans_kernel<<<dim3(16, 16), 256, 0, stream>>>(Wq, Wqkvt,              512, 512);
    wtrans_kernel<<<dim3(16, 16), 256, 0, stream>>>(Wk, Wqkvt + 512 * 512,  512, 512);
    wtrans_kernel<<<dim3(16, 16), 256, 0, stream>>>(Wv, Wqkvt + 1024 * 512, 512, 512);
    wtrans_kernel<<<dim3(64, 16), 256, 0, stream>>>(W1, W1t, 512, 2048);
    wtrans_kernel<<<dim3(16, 64), 256, 0, stream>>>(W2, W2t, 2048, 512);
    // B. fused QKV projection: C[4096][1536] (cols 0-511 Q from inputs, 512-1535 K,V from encoder)
    gemm_kernel<64, true, false, false, true><<<dim3(64, 12), 256, 0, stream>>>(
        Xb, Eb, 4, Wqkvt, nullptr, QKVb, 512, 1536);
    // C. V -> Vt[bh][64][2048]
    vtrans_kernel<<<dim3(32, 16), 256, 0, stream>>>(QKVb, Vtb);
    // D. flash attention (kv-split 2) -> bf16 partials + (m,l)
    flash_kernel<<<dim3(32, 16, 2), 256, 0, stream>>>(QKVb, Vtb, Opart, mlbuf);
    // D2. combine partials -> O (= d_out) f32 [4096][512]
    combine_kernel<<<8192, 256, 0, stream>>>(Opart, mlbuf, Obuf);
    // E. out1 = LN(O + inputs) -> bf16 only
    add_ln_kernel<false><<<4096, 128, 0, stream>>>(Obuf, inputs, ln1g, ln1b, nullptr, out1b);
    // F. H = relu(out1 @ W1 + b1)  [4096][2048] bf16
    gemm_kernel<128, false, true, true, true><<<dim3(32, 16), 256, 0, stream>>>(
        out1b, nullptr, 0, W1t, b1, Hb, 512, 2048);
    // G. FF = H @ W2 + b2  [4096][512] f32 -> d_out
    gemm_kernel<64, false, true, false, false><<<dim3(64, 4), 256, 0, stream>>>(
        Hb, nullptr, 0, W2t, b2, FF, 2048, 512);
    // H. final = LN(FF + out1b) -> d_out (in-place, row-local)
    add_ln_kernel<true><<<4096, 128, 0, stream>>>(FF, out1b, ln2g, ln2b, (float*)d_out, nullptr);
}